// Round 16
// baseline (830.811 us; speedup 1.0000x reference)
//
#include <hip/hip_runtime.h>

#define TOKENS  8192
#define IN_DIM  4096
#define OUT_DIM 12288
#define GRP     128

typedef __attribute__((ext_vector_type(8))) short  short8;    // 8 bf16
typedef __attribute__((ext_vector_type(8))) unsigned short ushort8;
typedef __attribute__((ext_vector_type(4))) float  f32x4;     // MFMA acc

#define BARRIER() asm volatile("s_barrier" ::: "memory")
#define LGKM0()   asm volatile("s_waitcnt lgkmcnt(0)" ::: "memory")

__device__ __forceinline__ unsigned short f2bf(float f) {
    union { float f; unsigned int i; } x; x.f = f;
    unsigned int r = x.i + 0x7FFFu + ((x.i >> 16) & 1u);   // RNE
    return (unsigned short)(r >> 16);
}

__device__ __forceinline__ void gload_lds16(const void* g, void* l) {
    __builtin_amdgcn_global_load_lds(
        (const __attribute__((address_space(1))) void*)g,
        (__attribute__((address_space(3))) void*)l, 16, 0, 0);
}

// ---------------------------------------------------------------------------
// Merged prep kernel (r15, proven): dequant W -> bf16 (pqs folded) + cvt A.
// ---------------------------------------------------------------------------
#define DQ_BLOCKS 24576   // (OUT/2)*(IN/4)/256
#define CV_BLOCKS 16384   // TOKENS*IN/(256*8)

__global__ void prep_kernel(const int* __restrict__ wp,
                            const float* __restrict__ wsc,
                            const float* __restrict__ pqs,
                            const float* __restrict__ hid,
                            unsigned short* __restrict__ Wd,
                            unsigned short* __restrict__ Abf) {
    if (blockIdx.x < DQ_BLOCKS) {
        int idx = blockIdx.x * blockDim.x + threadIdx.x;
        int p  = idx >> 10;
        int i0 = (idx & 1023) << 2;
        int g  = i0 >> 7;
        const int4 w = *reinterpret_cast<const int4*>(wp + (size_t)p * IN_DIM + i0);
        float slo = wsc[(size_t)(2 * p)     * (IN_DIM / GRP) + g];
        float shi = wsc[(size_t)(2 * p + 1) * (IN_DIM / GRP) + g];
        float4 q = *reinterpret_cast<const float4*>(pqs + i0);
        float qf[4] = { q.x, q.y, q.z, q.w };
        int   wv[4] = { w.x, w.y, w.z, w.w };
        ushort4 lo, hi;
        unsigned short* lop = (unsigned short*)&lo;
        unsigned short* hig = (unsigned short*)&hi;
#pragma unroll
        for (int j = 0; j < 4; ++j) {
            lop[j] = f2bf((float)(( wv[j]       & 0xF) - 8) * slo * qf[j]);
            hig[j] = f2bf((float)(((wv[j] >> 4) & 0xF) - 8) * shi * qf[j]);
        }
        *reinterpret_cast<ushort4*>(Wd + (size_t)(2 * p)     * IN_DIM + i0) = lo;
        *reinterpret_cast<ushort4*>(Wd + (size_t)(2 * p + 1) * IN_DIM + i0) = hi;
    } else {
        size_t base = ((size_t)(blockIdx.x - DQ_BLOCKS) * blockDim.x + threadIdx.x) * 8;
        float4 a = *reinterpret_cast<const float4*>(hid + base);
        float4 b = *reinterpret_cast<const float4*>(hid + base + 4);
        ushort8 v;
        v[0] = f2bf(a.x); v[1] = f2bf(a.y); v[2] = f2bf(a.z); v[3] = f2bf(a.w);
        v[4] = f2bf(b.x); v[5] = f2bf(b.y); v[6] = f2bf(b.z); v[7] = f2bf(b.w);
        *reinterpret_cast<ushort8*>(Abf + base) = v;
    }
}

// ===========================================================================
// r16: faithful m201-template port. 256x256, BK=64, 8 waves (2Mx4N),
// per-wave 128x64. PHASES = OUTPUT QUADRANTS (mq,nq) at FULL K=64:
//  ph1 (mq0,nq0): read A-mq0 [8] + B-nq0 [4]; stage B_own(u+1); 2-bar MFMA
//  ph2 (mq0,nq1): read B-nq1 [4]; 2-bar MFMA (A cached)
//  ph3 (mq1,nq0): read A-mq1 [8]; 2-bar MFMA (B-nq0 cached)
//  ph4 (mq1,nq1): no reads; stage A_own(u+2); MFMA; boundary vmcnt; BAR
// GROUP-AFFINITY STAGING: consumers==stagers. A-half wm staged by the 4
// waves with that wm (gi=wid&3); B-half bg=wn>>1 staged by its 4 waves
// (gi=((wid>>2)<<1)|(wid&1)). 4 gloads/thread per stage (16KB/group).
// Per-wave vmcnt ledger (4 loads/stage): at u-ph4 boundary outstanding =
// [A(u+1)@(u-1)ph4(landed)], B(u+1)@u-ph1, A(u+2)@u-ph4 -> vmcnt(4) drains
// through B(u+1), leaves A(u+2) flying. Tails: u+2>=NT -> vmcnt(0).
// WAR audit: B-stage@ph1 overwrites B(u-1), last ds_read (u-1)-ph2 (lgkm-
// drained, 3 barriers back); A-stage@ph4 overwrites A(u), last read u-ph3
// (drained at ph3's LGKM0, 1 barrier back). Prologue: A(0),B(0),A(1),
// vmcnt(4), BAR (steady-state-consistent).
// ===========================================================================
#define BM 256
#define BN 256
#define BK 64
#define NT (IN_DIM / BK)   // 64

// stage one 16KB group-half (128 rows x 64 k) of tile t into [kh] regions.
// regionA/regionB = base of lds[buf][mat] = 2 khalf regions of 16KB each.
// growbase = group's first row within the 256-row tile; gti = gi*64+lane.
__device__ __forceinline__ void stage_group(const unsigned short* gbase,
                                            int blockbase, int growbase,
                                            int t, char* mat_base, int gti) {
#pragma unroll
    for (int c = 0; c < 4; ++c) {
        int kh   = c >> 1;
        int off  = (c & 1) * 4096 + gti * 16;        // [0,8192) in the kh piece
        int row  = growbase + (off >> 6);            // global row in 256-tile
        int slot = (off >> 4) & 3;
        int col  = t * 64 + kh * 32 + ((slot ^ ((row >> 1) & 3)) << 3); // inv swz
        gload_lds16(gbase + (size_t)(blockbase + row) * IN_DIM + col,
                    mat_base + kh * 16384 + row * 64 + (slot << 4));
    }
}

__global__ __launch_bounds__(512, 2) void gemm8p_kernel(
    const unsigned short* __restrict__ A,   // [TOKENS][IN] bf16
    const unsigned short* __restrict__ B,   // [OUT][IN] bf16
    float* __restrict__ C) {                // [TOKENS][OUT] f32

    __shared__ char lds[2][2][2][16384];    // [buf][mat A=0/B=1][khalf][16KB]

    const int tid  = threadIdx.x;
    const int lane = tid & 63;
    const int wid  = tid >> 6;
    const int wm   = wid >> 2;              // 0..1  (A-half group)
    const int wn   = wid & 3;               // 0..3
    const int bg   = wn >> 1;               // 0..1  (B-half group)
    const int lq   = lane & 15;
    const int lr   = lane >> 4;             // 0..3
    const int sw   = (lr ^ ((lq >> 1) & 3)) << 4;   // swizzled slot byte offset

    const int gtiA = (wn) * 64 + lane;                      // 0..255 in A-group
    const int gtiB = (((wid >> 2) << 1) | (wid & 1)) * 64 + lane; // in B-group

    // grid 1536 = 8 * 192: bijective XCD swizzle
    int bid = blockIdx.x;
    int swz = (bid & 7) * 192 + (bid >> 3);
    const int brow = (swz / (OUT_DIM / BN)) * BM;
    const int bcol = (swz % (OUT_DIM / BN)) * BN;

    f32x4 acc[8][4] = {};
    short8 aF[4][2], bF0[2][2], bF1[2][2];   // [frag][khalf]

    // ---- prologue: A(0), B(0), A(1); vmcnt(4) leaves A(1); BAR ----
    stage_group(A, brow, wm * 128, 0, &lds[0][0][0][0], gtiA);
    stage_group(B, bcol, bg * 128, 0, &lds[0][1][0][0], gtiB);
    stage_group(A, brow, wm * 128, 1, &lds[1][0][0][0], gtiA);
    asm volatile("s_waitcnt vmcnt(4)" ::: "memory");
    BARRIER();

    for (int u = 0; u < NT; ++u) {
        const int p = u & 1, q = p ^ 1;
        char* pA = &lds[p][0][0][0];
        char* pB = &lds[p][1][0][0];

        // ---------- ph1 (mq0,nq0): read A-mq0 + B-nq0; stage B_own(u+1) ----
#pragma unroll
        for (int m = 0; m < 4; ++m)
#pragma unroll
            for (int kk = 0; kk < 2; ++kk)
                aF[m][kk] = *reinterpret_cast<const short8*>(
                    pA + kk * 16384 + (wm * 128 + m * 16 + lq) * 64 + sw);
#pragma unroll
        for (int n = 0; n < 2; ++n)
#pragma unroll
            for (int kk = 0; kk < 2; ++kk)
                bF0[n][kk] = *reinterpret_cast<const short8*>(
                    pB + kk * 16384 + (wn * 64 + n * 16 + lq) * 64 + sw);
        if (u + 1 < NT)
            stage_group(B, bcol, bg * 128, u + 1, &lds[q][1][0][0], gtiB);
        BARRIER();
        LGKM0();
        __builtin_amdgcn_s_setprio(1);
#pragma unroll
        for (int m = 0; m < 4; ++m)
#pragma unroll
            for (int n = 0; n < 2; ++n)
#pragma unroll
                for (int kk = 0; kk < 2; ++kk)
                    acc[m][n] = __builtin_amdgcn_mfma_f32_16x16x32_bf16(
                        aF[m][kk], bF0[n][kk], acc[m][n], 0, 0, 0);
        __builtin_amdgcn_s_setprio(0);
        BARRIER();

        // ---------- ph2 (mq0,nq1): read B-nq1; MFMA (A cached) ----
#pragma unroll
        for (int n = 0; n < 2; ++n)
#pragma unroll
            for (int kk = 0; kk < 2; ++kk)
                bF1[n][kk] = *reinterpret_cast<const short8*>(
                    pB + kk * 16384 + (wn * 64 + 32 + n * 16 + lq) * 64 + sw);
        BARRIER();
        LGKM0();
        __builtin_amdgcn_s_setprio(1);
#pragma unroll
        for (int m = 0; m < 4; ++m)
#pragma unroll
            for (int n = 0; n < 2; ++n)
#pragma unroll
                for (int kk = 0; kk < 2; ++kk)
                    acc[m][n + 2] = __builtin_amdgcn_mfma_f32_16x16x32_bf16(
                        aF[m][kk], bF1[n][kk], acc[m][n + 2], 0, 0, 0);
        __builtin_amdgcn_s_setprio(0);
        BARRIER();

        // ---------- ph3 (mq1,nq0): read A-mq1; MFMA (B-nq0 cached) ----
#pragma unroll
        for (int m = 0; m < 4; ++m)
#pragma unroll
            for (int kk = 0; kk < 2; ++kk)
                aF[m][kk] = *reinterpret_cast<const short8*>(
                    pA + kk * 16384 + (wm * 128 + 64 + m * 16 + lq) * 64 + sw);
        BARRIER();
        LGKM0();
        __builtin_amdgcn_s_setprio(1);
#pragma unroll
        for (int m = 0; m < 4; ++m)
#pragma unroll
            for (int n = 0; n < 2; ++n)
#pragma unroll
                for (int kk = 0; kk < 2; ++kk)
                    acc[m + 4][n] = __builtin_amdgcn_mfma_f32_16x16x32_bf16(
                        aF[m][kk], bF0[n][kk], acc[m + 4][n], 0, 0, 0);
        __builtin_amdgcn_s_setprio(0);
        BARRIER();

        // ---------- ph4 (mq1,nq1): stage A_own(u+2); MFMA; boundary ----
        if (u + 2 < NT)
            stage_group(A, brow, wm * 128, u + 2, &lds[p][0][0][0], gtiA);
        BARRIER();
        __builtin_amdgcn_s_setprio(1);
#pragma unroll
        for (int m = 0; m < 4; ++m)
#pragma unroll
            for (int n = 0; n < 2; ++n)
#pragma unroll
                for (int kk = 0; kk < 2; ++kk)
                    acc[m + 4][n + 2] = __builtin_amdgcn_mfma_f32_16x16x32_bf16(
                        aF[m][kk], bF1[n][kk], acc[m + 4][n + 2], 0, 0, 0);
        __builtin_amdgcn_s_setprio(0);
        // boundary: drain through B(u+1); keep A(u+2) in flight
        if (u + 2 < NT) { asm volatile("s_waitcnt vmcnt(4)" ::: "memory"); }
        else            { asm volatile("s_waitcnt vmcnt(0)" ::: "memory"); }
        BARRIER();
    }

    // ---- epilogue: C/D layout col=lane&15, row=(lane>>4)*4+j ----
#pragma unroll
    for (int m = 0; m < 8; ++m)
#pragma unroll
        for (int n = 0; n < 4; ++n)
#pragma unroll
            for (int j = 0; j < 4; ++j) {
                int row = brow + wm * 128 + m * 16 + lr * 4 + j;
                int col = bcol + wn * 64 + n * 16 + lq;
                C[(size_t)row * OUT_DIM + col] = acc[m][n][j];
            }
}

// ---------------------------------------------------------------------------
// Fallback (ws too small): round-4 proven 128x128 2-phase kernel.
// ---------------------------------------------------------------------------
template <bool CONV_A, bool FUSED_B>
__global__ __launch_bounds__(256) void gemm_fb_kernel(
    const void* __restrict__ Ap, const unsigned short* __restrict__ Bd,
    const int* __restrict__ Wp, const float* __restrict__ wsc,
    const float* __restrict__ pqs, float* __restrict__ C) {
    __shared__ short sA[128 * 64];
    __shared__ short sB[128 * 64];
    const int tid  = threadIdx.x;
    const int lane = tid & 63;
    const int w    = tid >> 6;
    const int wr   = w >> 1, wc = w & 1;
    const int lr   = lane >> 4;
    const int lq   = lane & 15;
    const int nbn = OUT_DIM / 128;
    int bid = blockIdx.x;
    int swzb = (bid & 7) * ((TOKENS / 128) * nbn / 8) + (bid >> 3);
    const int brow = (swzb / nbn) * 128;
    const int bcol = (swzb % nbn) * 128;
    f32x4 acc[4][4] = {};
    for (int k0 = 0; k0 < IN_DIM; k0 += 64) {
#pragma unroll
        for (int c = 0; c < 4; ++c) {
            int off  = c * 4096 + tid * 16;
            int r    = off >> 7;
            if constexpr (CONV_A) {
                int e = (off & 127) >> 1;
                const float* src = (const float*)Ap + (size_t)(brow + r) * IN_DIM + k0 + e;
                float4 f0 = *reinterpret_cast<const float4*>(src);
                float4 f1 = *reinterpret_cast<const float4*>(src + 4);
                ushort8 v;
                v[0] = f2bf(f0.x); v[1] = f2bf(f0.y); v[2] = f2bf(f0.z); v[3] = f2bf(f0.w);
                v[4] = f2bf(f1.x); v[5] = f2bf(f1.y); v[6] = f2bf(f1.z); v[7] = f2bf(f1.w);
                *reinterpret_cast<ushort8*>((char*)sA + off) = v;
            } else {
                int colb = off & 127;
                gload_lds16((const char*)Ap + ((size_t)(brow + r) * IN_DIM + k0) * 2 + colb,
                            (char*)sA + off);
            }
            if constexpr (!FUSED_B) {
                int colb = off & 127;
                gload_lds16((const char*)Bd + ((size_t)(bcol + r) * IN_DIM + k0) * 2 + colb,
                            (char*)sB + off);
            }
        }
        if constexpr (FUSED_B) {
#pragma unroll
            for (int c = 0; c < 4; ++c) {
                int pr = c * 16 + (tid >> 4);
                int i0 = (tid & 15) * 4;
                int gp = (bcol >> 1) + pr;
                int gk = k0 + i0;
                int4 wv = *reinterpret_cast<const int4*>(Wp + (size_t)gp * IN_DIM + gk);
                int g = gk >> 7;
                float slo = wsc[(size_t)(2 * gp)     * (IN_DIM / GRP) + g];
                float shi = wsc[(size_t)(2 * gp + 1) * (IN_DIM / GRP) + g];
                float4 qv = *reinterpret_cast<const float4*>(pqs + gk);
                float qf[4] = { qv.x, qv.y, qv.z, qv.w };
                int wi[4] = { wv.x, wv.y, wv.z, wv.w };
                ushort4 lo, hi;
                unsigned short* lop = (unsigned short*)&lo;
                unsigned short* hig = (unsigned short*)&hi;
#pragma unroll
                for (int j = 0; j < 4; ++j) {
                    lop[j] = f2bf((float)(( wi[j]       & 0xF) - 8) * slo * qf[j]);
                    hig[j] = f2bf((float)(((wi[j] >> 4) & 0xF) - 8) * shi * qf[j]);
                }
                *reinterpret_cast<ushort4*>(&sB[(2 * pr)     * 64 + i0]) = lo;
                *reinterpret_cast<ushort4*>(&sB[(2 * pr + 1) * 64 + i0]) = hi;
            }
        }
        __syncthreads();
#pragma unroll
        for (int kk = 0; kk < 64; kk += 32) {
            int ko = kk + lr * 8;
            short8 af[4], bf[4];
#pragma unroll
            for (int m = 0; m < 4; ++m)
                af[m] = *reinterpret_cast<const short8*>(&sA[(wr * 64 + m * 16 + lq) * 64 + ko]);
#pragma unroll
            for (int n = 0; n < 4; ++n)
                bf[n] = *reinterpret_cast<const short8*>(&sB[(wc * 64 + n * 16 + lq) * 64 + ko]);
#pragma unroll
            for (int m = 0; m < 4; ++m)
#pragma unroll
                for (int n = 0; n < 4; ++n)
                    acc[m][n] = __builtin_amdgcn_mfma_f32_16x16x32_bf16(
                        af[m], bf[n], acc[m][n], 0, 0, 0);
        }
        __syncthreads();
    }
#pragma unroll
    for (int m = 0; m < 4; ++m)
#pragma unroll
        for (int n = 0; n < 4; ++n)
#pragma unroll
            for (int j = 0; j < 4; ++j) {
                int row = brow + wr * 64 + m * 16 + lr * 4 + j;
                int col = bcol + wc * 64 + n * 16 + lq;
                C[(size_t)row * OUT_DIM + col] = acc[m][n][j];
            }
}

extern "C" void kernel_launch(void* const* d_in, const int* in_sizes, int n_in,
                              void* d_out, int out_size, void* d_ws, size_t ws_size,
                              hipStream_t stream) {
    // Resolve inputs by element count (all distinct)
    const void* p_hidden = nullptr; const void* p_weight = nullptr;
    const void* p_wscale = nullptr; const void* p_pqs = nullptr;
    for (int i = 0; i < n_in; ++i) {
        switch (in_sizes[i]) {
            case 33554432: p_hidden = d_in[i]; break;
            case 25165824: p_weight = d_in[i]; break;
            case 393216:   p_wscale = d_in[i]; break;
            case 4096:     p_pqs    = d_in[i]; break;
            default: break;
        }
    }
    if (!p_hidden || !p_weight || !p_wscale || !p_pqs) {
        p_hidden = d_in[0]; p_weight = d_in[1]; p_wscale = d_in[2]; p_pqs = d_in[3];
    }
    const float* hidden = (const float*)p_hidden;
    const int*   weight = (const int*)p_weight;
    const float* wscale = (const float*)p_wscale;
    const float* pqs    = (const float*)p_pqs;
    float*       out    = (float*)d_out;

    const size_t wd_bytes = (size_t)OUT_DIM * IN_DIM * 2;     // 96 MB bf16 W
    const size_t ab_bytes = (size_t)TOKENS * IN_DIM * 2;      // 64 MB bf16 A

    if (ws_size >= wd_bytes + ab_bytes) {
        unsigned short* Wd  = (unsigned short*)d_ws;
        unsigned short* Abf = (unsigned short*)((char*)d_ws + wd_bytes);
        prep_kernel<<<DQ_BLOCKS + CV_BLOCKS, 256, 0, stream>>>(
            weight, wscale, pqs, hidden, Wd, Abf);
        gemm8p_kernel<<<(TOKENS / BM) * (OUT_DIM / BN), 512, 0, stream>>>(Abf, Wd, out);
    } else if (ws_size >= wd_bytes) {
        unsigned short* Wd = (unsigned short*)d_ws;
        prep_kernel<<<DQ_BLOCKS, 256, 0, stream>>>(
            weight, wscale, pqs, hidden, Wd, nullptr);
        gemm_fb_kernel<true, false><<<(TOKENS / 128) * (OUT_DIM / 128), 256, 0, stream>>>(
            hidden, Wd, nullptr, nullptr, nullptr, out);
    } else {
        gemm_fb_kernel<true, true><<<(TOKENS / 128) * (OUT_DIM / 128), 256, 0, stream>>>(
            hidden, nullptr, weight, wscale, pqs, out);
    }
}